// Round 3
// baseline (87.502 us; speedup 1.0000x reference)
//
#include <hip/hip_runtime.h>

// BilateralBlur 7x7, sigma_color=0.1 (l1), sigma_space=1.5, reflect pad.
// (B=4, C=3, H=512, W=512) float32.
//
// R3 design (post-mortem driven):
// - Harness floor: ~45us of dur_us is the harness's 268MB ws re-poison +
//   input restore (rocprof top-5 = fillBufferAligned @42.6us; our kernel
//   is below the top-5 cut). Kernel itself was ~40us in R1/R2.
// - R2 failure: compile-time trip count -> compiler fully unrolled the
//   "rolled" dy loop -> 49 hoisted float4 taps -> ~200 VGPR -> 2 waves/SIMD.
// - R3: y-column scheme. Each thread owns an 8-pixel column. Iterate the 14
//   tap-rows ONCE (#pragma unroll 1), 7 conflict-free ds_read_b128 per row,
//   and scatter each row's contribution into the <=7 pixels whose 7x7
//   window contains it (pixel index compile-time -> accs stay in VGPRs).
//   LDS reads/px: 28 -> 12.6; live taps capped at 7 float4.
// - Channels interleaved in 16B LDS slots: 1 tap = 1 ds_read_b128 at 16B
//   lane stride (conflict-free). Spatial kernel unnormalized (cancels).
// - exp via v_exp_f32: arg = -(C1*l1)^2 with C1 = sqrt(50*log2(e)).

constexpr int KR  = 3;
constexpr int CH  = 3;
constexpr int IMH = 512, IMW = 512;
constexpr int BX  = 32;           // threads in x
constexpr int BYT = 2;            // thread rows
constexpr int PY  = 8;            // pixels per thread (y-column)
constexpr int TLH = BYT * PY;     // 16 output rows per block
constexpr int TW  = BX + 2 * KR;  // 38
constexpr int TH  = TLH + 2 * KR; // 22
constexpr int NTHR = BX * BYT;    // 64

__device__ __constant__ float c_w1d[7] = {
    0.13533528f, 0.41111229f, 0.80073744f, 1.0f,
    0.80073744f, 0.41111229f, 0.13533528f};

__global__ __launch_bounds__(NTHR)
void bilateral7_kernel(const float* __restrict__ in, float* __restrict__ out) {
    __shared__ float tile[TH][TW][4];   // [y][x][c], slot 3 = 16B pad

    const int tx = threadIdx.x, tyw = threadIdx.y;
    const int x0 = blockIdx.x * BX, y0 = blockIdx.y * TLH;
    const int b  = blockIdx.z;
    const size_t hw = (size_t)IMH * IMW;
    const float* __restrict__ inb = in + (size_t)b * CH * hw;
    const int tid = tyw * BX + tx;

    // Stage tile (reflect). Consecutive i -> consecutive gx: each of the 3
    // channel loads is coalesced; ds_write_b128 at 16B stride conflict-free.
    for (int i = tid; i < TH * TW; i += NTHR) {
        const int iy = i / TW, ix = i - iy * TW;
        int gy = y0 + iy - KR, gx = x0 + ix - KR;
        gy = gy < 0 ? -gy : (gy >= IMH ? 2 * IMH - 2 - gy : gy);
        gx = gx < 0 ? -gx : (gx >= IMW ? 2 * IMW - 2 - gx : gx);
        const size_t o = (size_t)gy * IMW + gx;
        *(float4*)&tile[iy][ix][0] =
            make_float4(inb[o], inb[hw + o], inb[2 * hw + o], 0.f);
    }
    __syncthreads();

    const int rbase = tyw * PY;

    float4 ctr[PY];
    #pragma unroll
    for (int p = 0; p < PY; ++p)
        ctr[p] = *(const float4*)&tile[rbase + p + KR][tx + KR][0];

    float ax[PY], ay[PY], az[PY], aw[PY];
    #pragma unroll
    for (int p = 0; p < PY; ++p) { ax[p] = ay[p] = az[p] = aw[p] = 0.f; }

    const float wx[7] = {0.13533528f, 0.41111229f, 0.80073744f, 1.0f,
                         0.80073744f, 0.41111229f, 0.13533528f};
    const float C1 = 8.4932187e0f;   // sqrt(50*log2(e)); arg = -(C1*l1)^2

    #pragma unroll 1                 // MUST stay rolled: caps live taps at 7
    for (int r = 0; r < PY + 2 * KR; ++r) {   // 14 tap-rows
        float4 t[7];
        #pragma unroll
        for (int d = 0; d < 7; ++d)
            t[d] = *(const float4*)&tile[rbase + r][tx + d][0];

        #pragma unroll
        for (int p = 0; p < PY; ++p) {        // compile-time pixel index
            const int dy = r - p;             // runtime-uniform
            if (dy >= 0 && dy <= 2 * KR) {    // uniform branch
                const float wy = c_w1d[dy];
                #pragma unroll
                for (int d = 0; d < 7; ++d) {
                    const float4 q = t[d];
                    const float l1 = fabsf(q.x - ctr[p].x)
                                   + fabsf(q.y - ctr[p].y)
                                   + fabsf(q.z - ctr[p].z);
                    const float s = l1 * C1;
                    const float e = __builtin_amdgcn_exp2f(s * -s);
                    const float w = (wy * wx[d]) * e;
                    ax[p] = fmaf(q.x, w, ax[p]);
                    ay[p] = fmaf(q.y, w, ay[p]);
                    az[p] = fmaf(q.z, w, az[p]);
                    aw[p] += w;
                }
            }
        }
    }

    const int x = x0 + tx;
    #pragma unroll
    for (int p = 0; p < PY; ++p) {
        const int y = y0 + rbase + p;
        const float inv = __fdividef(1.0f, aw[p]);   // aw >= 1 (center tap)
        const size_t o = (size_t)b * CH * hw + (size_t)y * IMW + x;
        out[o]          = ax[p] * inv;
        out[o + hw]     = ay[p] * inv;
        out[o + 2 * hw] = az[p] * inv;
    }
}

extern "C" void kernel_launch(void* const* d_in, const int* in_sizes, int n_in,
                              void* d_out, int out_size, void* d_ws, size_t ws_size,
                              hipStream_t stream) {
    const float* in  = (const float*)d_in[0];
    float*       out = (float*)d_out;
    const int B = in_sizes[0] / (CH * IMH * IMW);     // 4
    dim3 grid(IMW / BX, IMH / TLH, B);                // (16, 32, 4) = 2048
    dim3 block(BX, BYT, 1);
    bilateral7_kernel<<<grid, block, 0, stream>>>(in, out);
}

// Round 4
// 84.018 us; speedup vs baseline: 1.0415x; 1.0415x over previous
//
#include <hip/hip_runtime.h>

// BilateralBlur 7x7, sigma_color=0.1 (l1), sigma_space=1.5, reflect pad.
// (B=4, C=3, H=512, W=512) float32.
//
// R4 design (discriminating experiment):
// - dur_us has been 84.6/87.4/87.5 across three structurally different
//   kernels; rocprof top-5 is always the harness's 268MB ws re-poison
//   (42.6us @ 6.3TB/s) and our kernel never shows (<42us). Theory: dur_us
//   carries ~75-80us of fixed harness reset cost; kernel is near its
//   ~10us VALU floor (617M lane-ops / 78.6T + 2.6us v_exp_f32).
// - Residual alternative: R3 was grid-starved (64-thr blocks, 2 waves/SIMD).
//   R4 fixes that: 256-thr blocks (4 waves), PY=4 px/thread column, grid
//   1024 blocks -> 16 waves/CU (4/SIMD), VGPR ~85, LDS 23KB.
// - PRE-COMMITTED READ: dur_us ~60-65 => kernel time was real, keep tuning.
//   dur_us 85-89 => harness floor confirmed => ROOFLINE next round.
//
// Mechanics (carried from R3):
// - Channels interleaved in 16B LDS slots: 1 tap = 1 ds_read_b128 at 16B
//   lane stride (conflict-free). Row loop rolled (#pragma unroll 1) so only
//   7 float4 taps are live; pixel index compile-time (accs stay in VGPRs).
// - Spatial kernel UNNORMALIZED (normalization cancels in the ratio).
// - exp via v_exp_f32: arg = -(C1*l1)^2, C1 = sqrt(50*log2(e)).

constexpr int KR  = 3;
constexpr int CH  = 3;
constexpr int IMH = 512, IMW = 512;
constexpr int BX  = 32;           // threads in x
constexpr int BYT = 8;            // thread rows
constexpr int PY  = 4;            // pixels per thread (y-column)
constexpr int TLH = BYT * PY;     // 32 output rows per block
constexpr int TW  = BX + 2 * KR;  // 38
constexpr int TH  = TLH + 2 * KR; // 38
constexpr int NTHR = BX * BYT;    // 256

__device__ __constant__ float c_w1d[7] = {
    0.13533528f, 0.41111229f, 0.80073744f, 1.0f,
    0.80073744f, 0.41111229f, 0.13533528f};

__global__ __launch_bounds__(NTHR)
void bilateral7_kernel(const float* __restrict__ in, float* __restrict__ out) {
    __shared__ float tile[TH][TW][4];   // [y][x][c], slot 3 = 16B pad; 23.1KB

    const int tx = threadIdx.x, tyw = threadIdx.y;
    const int x0 = blockIdx.x * BX, y0 = blockIdx.y * TLH;
    const int b  = blockIdx.z;
    const size_t hw = (size_t)IMH * IMW;
    const float* __restrict__ inb = in + (size_t)b * CH * hw;
    const int tid = tyw * BX + tx;

    // Stage tile (reflect). Consecutive i -> consecutive gx -> coalesced
    // per-channel loads; ds_write_b128 at 16B lane stride conflict-free.
    for (int i = tid; i < TH * TW; i += NTHR) {
        const int iy = i / TW, ix = i - iy * TW;
        int gy = y0 + iy - KR, gx = x0 + ix - KR;
        gy = gy < 0 ? -gy : (gy >= IMH ? 2 * IMH - 2 - gy : gy);
        gx = gx < 0 ? -gx : (gx >= IMW ? 2 * IMW - 2 - gx : gx);
        const size_t o = (size_t)gy * IMW + gx;
        *(float4*)&tile[iy][ix][0] =
            make_float4(inb[o], inb[hw + o], inb[2 * hw + o], 0.f);
    }
    __syncthreads();

    const int rbase = tyw * PY;   // first output row (tile coords) of column

    float4 ctr[PY];
    #pragma unroll
    for (int p = 0; p < PY; ++p)
        ctr[p] = *(const float4*)&tile[rbase + p + KR][tx + KR][0];

    float ax[PY], ay[PY], az[PY], aw[PY];
    #pragma unroll
    for (int p = 0; p < PY; ++p) { ax[p] = ay[p] = az[p] = aw[p] = 0.f; }

    const float wx[7] = {0.13533528f, 0.41111229f, 0.80073744f, 1.0f,
                         0.80073744f, 0.41111229f, 0.13533528f};
    const float C1 = 8.4932187e0f;   // sqrt(50*log2(e)); arg = -(C1*l1)^2

    #pragma unroll 1                 // keep rolled: caps live taps at 7
    for (int r = 0; r < PY + 2 * KR; ++r) {   // 10 tap-rows in column window
        float4 t[7];
        #pragma unroll
        for (int d = 0; d < 7; ++d)
            t[d] = *(const float4*)&tile[rbase + r][tx + d][0];

        #pragma unroll
        for (int p = 0; p < PY; ++p) {        // compile-time pixel index
            const int dy = r - p;             // wave-uniform
            if (dy >= 0 && dy <= 2 * KR) {    // uniform branch (s_cbranch)
                const float wy = c_w1d[dy];
                #pragma unroll
                for (int d = 0; d < 7; ++d) {
                    const float4 q = t[d];
                    const float l1 = fabsf(q.x - ctr[p].x)
                                   + fabsf(q.y - ctr[p].y)
                                   + fabsf(q.z - ctr[p].z);
                    const float s = l1 * C1;
                    const float e = __builtin_amdgcn_exp2f(s * -s);
                    const float w = (wy * wx[d]) * e;
                    ax[p] = fmaf(q.x, w, ax[p]);
                    ay[p] = fmaf(q.y, w, ay[p]);
                    az[p] = fmaf(q.z, w, az[p]);
                    aw[p] += w;
                }
            }
        }
    }

    const int x = x0 + tx;
    #pragma unroll
    for (int p = 0; p < PY; ++p) {
        const int y = y0 + rbase + p;
        const float inv = __fdividef(1.0f, aw[p]);   // aw >= 1 (center tap)
        const size_t o = (size_t)b * CH * hw + (size_t)y * IMW + x;
        out[o]          = ax[p] * inv;               // coalesced across tx
        out[o + hw]     = ay[p] * inv;
        out[o + 2 * hw] = az[p] * inv;
    }
}

extern "C" void kernel_launch(void* const* d_in, const int* in_sizes, int n_in,
                              void* d_out, int out_size, void* d_ws, size_t ws_size,
                              hipStream_t stream) {
    const float* in  = (const float*)d_in[0];
    float*       out = (float*)d_out;
    const int B = in_sizes[0] / (CH * IMH * IMW);     // 4
    dim3 grid(IMW / BX, IMH / TLH, B);                // (16, 16, 4) = 1024
    dim3 block(BX, BYT, 1);
    bilateral7_kernel<<<grid, block, 0, stream>>>(in, out);
}